// Round 6
// baseline (323.789 us; speedup 1.0000x reference)
//
#include <hip/hip_runtime.h>

// LightGCN: x0 = dropout(concat(user,item)); out = (x0 + A x0 + A^2 x0 + A^3 x0)/4
// R14: R13 (degree-equalized wave scheduling) with the coverage bug fixed.
//   R13 failure post-mortem: spmm grid covered 150016 perm slots but perm is
//   a permutation of NB*1024=150528 slots; bucket 146's 528 degree-0 dummy
//   rows sort to the FRONT of its region, pushing ~500 real rows past the
//   grid end -> never computed -> combine read stale stg data (aliased over
//   Y1h) as fp16 -> NaN. Fix: grid = NB*1024/32 = 4704 blocks (full perm
//   coverage); dummies filtered by the existing row>=NN check.
// R13 theory (unchanged): per-group edge loop is divergent — wave runs until
//   its LONGEST of 8 rows finishes (E[max over 8 Poisson(16)] ~ 3.2 batches
//   vs E=2.5 -> ~29% masked-slot waste). k_bsort counting-sorts each bucket's
//   1024 rows by degree (64 classes, LDS) into perm[]; spmm processes
//   perm[vrow] so a wave's 8 rows have ~equal degree.
// fp16 intermediates (R9): gather granule 128B, working set 19.2MB.
// Preproc (R12): dropout fused into k_pre; bscan folded into k_bsort.
// CSR build (R8): two-level counting sort.

static constexpr int NU = 100000;
static constexpr int NI = 50000;
static constexpr int NN = NU + NI;       // 150000
static constexpr int D  = 64;
static constexpr int E  = 2400000;
static constexpr int XN = NN * D;        // 9,600,000
static constexpr int XH = XN / 2;        // 4,800,000
static constexpr int NB = (NN + 1023) >> 10;   // 147 buckets
static constexpr int BPC = 24000;        // bucket staging cap (mean 16327, +59 sigma)
static constexpr int BIN_T = 256;
static constexpr int BIN_U = 16;
static constexpr int BIN_CHUNK = BIN_T * BIN_U;   // 4096
static constexpr int BGRID = (E + BIN_CHUNK - 1) / BIN_CHUNK;   // 586
static constexpr int DGRID = (XH + 255) / 256;                  // 18750

typedef _Float16 half_t;
typedef _Float16 half8 __attribute__((ext_vector_type(8)));

__device__ __forceinline__ unsigned rotl32(unsigned x, int r) {
    return (x << r) | (x >> (32 - r));
}

// Threefry-2x32, 20 rounds (jax_threefry_partitionable=True layout, verified R1).
__device__ __forceinline__ void threefry2x32(unsigned k0, unsigned k1,
                                             unsigned x0, unsigned x1,
                                             unsigned& o0, unsigned& o1) {
    unsigned ks2 = k0 ^ k1 ^ 0x1BD11BDAu;
    x0 += k0; x1 += k1;
#define TF_R(r) { x0 += x1; x1 = rotl32(x1, r); x1 ^= x0; }
    TF_R(13) TF_R(15) TF_R(26) TF_R(6)   x0 += k1;  x1 += ks2 + 1u;
    TF_R(17) TF_R(29) TF_R(16) TF_R(24)  x0 += ks2; x1 += k0 + 2u;
    TF_R(13) TF_R(15) TF_R(26) TF_R(6)   x0 += k0;  x1 += k1 + 3u;
    TF_R(17) TF_R(29) TF_R(16) TF_R(24)  x0 += k1;  x1 += ks2 + 4u;
    TF_R(13) TF_R(15) TF_R(26) TF_R(6)   x0 += ks2; x1 += k0 + 5u;
#undef TF_R
    o0 = x0; o1 = x1;
}

__device__ __forceinline__ float dropout_val(const float* __restrict__ ue,
                                             const float* __restrict__ ie,
                                             int i, unsigned bits) {
    float src = (i < NU * D) ? ue[i] : ie[i - NU * D];
    float u = __uint_as_float((bits >> 9) | 0x3f800000u) - 1.0f;
    return (u < 0.8f) ? (src / 0.8f) : 0.0f;
}

// Fused: blocks [0, BGRID) run the edge-binning pass; blocks [BGRID,
// BGRID+DGRID) run dropout-init. Bin blocks first (critical path to k_bsort);
// dropout streaming overlaps bin's atomic/scatter phase.
__global__ void __launch_bounds__(BIN_T) k_pre(const int* __restrict__ rows,
                                               const int* __restrict__ cols,
                                               const float* __restrict__ vals,
                                               int2* __restrict__ stg,
                                               int* __restrict__ pcnt,
                                               const float* __restrict__ ue,
                                               const float* __restrict__ ie,
                                               half_t* __restrict__ x0h) {
    __shared__ int lcnt[NB];
    __shared__ int gbase[NB];
    int tid = threadIdx.x;
    if (blockIdx.x >= BGRID) {
        // ---- dropout-init body ----
        int j = (blockIdx.x - BGRID) * BIN_T + tid;   // [0, XH)
        if (j >= XH) return;
        unsigned o0, o1, b0, b1;
        threefry2x32(0u, 42u, 0u, (unsigned)j, o0, o1);        b0 = o0 ^ o1;
        threefry2x32(0u, 42u, 0u, (unsigned)(j + XH), o0, o1); b1 = o0 ^ o1;
        x0h[j]      = (half_t)dropout_val(ue, ie, j, b0);
        x0h[j + XH] = (half_t)dropout_val(ue, ie, j + XH, b1);
        return;
    }
    // ---- bin body ----
    for (int i = tid; i < NB; i += BIN_T) lcnt[i] = 0;
    __syncthreads();
    int base = blockIdx.x * BIN_CHUNK;
    int lp[BIN_U];          // (bucket<<13) | loff, or -1 for tail
    int2 rec[BIN_U];
    #pragma unroll
    for (int u = 0; u < BIN_U; ++u) {
        int idx = base + u * BIN_T + tid;
        if (idx < E) {
            int row = rows[idx];
            int col = cols[idx];
            float v = vals[idx];
            unsigned q = min(__float2int_rn(v * 65536.f), 16383);
            int b = row >> 10;
            int loff = atomicAdd(&lcnt[b], 1);
            lp[u] = (b << 13) | loff;               // loff < 4096 < 8192
            rec[u] = make_int2((int)((q << 18) | (unsigned)col), row);
        } else {
            lp[u] = -1;
        }
    }
    __syncthreads();
    for (int i = tid; i < NB; i += BIN_T)
        gbase[i] = atomicAdd(&pcnt[i * 16], lcnt[i]);   // 64B-padded counters
    __syncthreads();
    #pragma unroll
    for (int u = 0; u < BIN_U; ++u) {
        if (lp[u] >= 0) {
            int b = lp[u] >> 13;
            int pos = gbase[b] + (lp[u] & 8191);
            if (pos < BPC) stg[(size_t)b * BPC + pos] = rec[u];
        }
    }
}

// One block per bucket. Wave 0 computes this bucket's global base (redundant
// 147-prefix, replaces k_bscan). Then: LDS hist of 1024 rows, block scan,
// write rp, scatter records into the bucket's dense [bb, bb+tot) ev region,
// and counting-sort the bucket's rows by degree into perm (spmm schedule).
__global__ void __launch_bounds__(1024) k_bsort(const int2* __restrict__ stg,
                                                const int* __restrict__ pcnt,
                                                int* __restrict__ rp,
                                                unsigned* __restrict__ ev,
                                                int* __restrict__ perm) {
    __shared__ int cnt[1024];
    __shared__ int wsum[16];
    __shared__ int sbb;
    __shared__ int dh[64];      // degree-class histogram
    __shared__ int dcur[64];    // degree-class cursors
    int b = blockIdx.x;
    int t = threadIdx.x;
    cnt[t] = 0;
    if (t < 64) dh[t] = 0;
    if (t < 64) {
        // exclusive prefix over buckets < b (one wave, <=3 values/lane)
        int a = 0;
        for (int i = t; i < b; i += 64) a += pcnt[i * 16];
        #pragma unroll
        for (int d = 1; d < 64; d <<= 1) a += __shfl_xor(a, d);
        if (t == 0) sbb = a;
    }
    if (b == 0 && t == 0) rp[NN] = E;    // sentinel
    __syncthreads();
    int tot = min(pcnt[b * 16], BPC);
    int bb = sbb;
    const int2* s = stg + (size_t)b * BPC;
    for (int i = t; i < tot; i += 1024)
        atomicAdd(&cnt[s[i].y & 1023], 1);
    __syncthreads();
    // Block-wide exclusive scan of cnt[1024]. v = this row's degree.
    int v = cnt[t];
    int lane = t & 63, w = t >> 6;
    int x = v;
    #pragma unroll
    for (int d = 1; d < 64; d <<= 1) {
        int y = __shfl_up(x, d);
        if (lane >= d) x += y;
    }
    if (lane == 63) wsum[w] = x;
    __syncthreads();
    if (w == 0 && lane < 16) {
        int sv = wsum[lane];
        #pragma unroll
        for (int d = 1; d < 16; d <<= 1) {
            int y = __shfl_up(sv, d);
            if (lane >= d) sv += y;
        }
        wsum[lane] = sv;
    }
    __syncthreads();
    int excl = ((w > 0) ? wsum[w - 1] : 0) + x - v;
    int row = (b << 10) + t;
    if (row < NN) rp[row] = bb + excl;
    // Degree counting-sort: class = min(deg,63).
    int cls = min(v, 63);
    atomicAdd(&dh[cls], 1);
    __syncthreads();
    cnt[t] = bb + excl;               // becomes the scatter cursor
    if (t < 64) {
        int a = dh[t];
        int sx = a;
        #pragma unroll
        for (int d = 1; d < 64; d <<= 1) {
            int y = __shfl_up(sx, d);
            if (lane >= d) sx += y;
        }
        dcur[t] = sx - a;             // exclusive class base
    }
    __syncthreads();
    // Scatter records into ev; emit degree-sorted row permutation.
    int p = atomicAdd(&dcur[cls], 1);
    perm[(b << 10) + p] = row;        // rows >= NN (dummies) included; spmm filters
    for (int i = t; i < tot; i += 1024) {
        int2 r = s[i];
        int pos = atomicAdd(&cnt[r.y & 1023], 1);
        ev[pos] = (unsigned)r.x;
    }
}

// Pull SpMM over exact CSR, fp16 x. Wave = 8 rows via degree-sorted perm
// (all 8 rows ~same degree -> no divergent-loop waste); 8-lane group owns a
// row (lane l holds dims [8l,8l+8), 16B). Per 8-edge batch: next batch's ev
// codes prefetched, 8 shfl broadcasts, 8 independent half8 gathers, fma block.
// Padded edges (idx>=cnt) have code 0 -> v=0, gather x[0] (L1-hot), harmless.
// MODE 0: yh = A*xh (fp16 out). MODE 1: out_f32 = (x0h + y1h + xh + A*xh)*0.25.
template <int MODE>
__global__ void __launch_bounds__(256) k_spmm(const int* __restrict__ rp,
                                              const unsigned* __restrict__ ev,
                                              const int* __restrict__ perm,
                                              const half_t* __restrict__ xh,
                                              half_t* __restrict__ yh,
                                              const half_t* __restrict__ x0h,
                                              const half_t* __restrict__ y1h,
                                              float* __restrict__ out) {
    int wid  = threadIdx.x >> 6;             // wave in block: 0..3
    int lane = threadIdx.x & 63;
    int g    = lane >> 3;                    // group (row slot) 0..7
    int l    = lane & 7;                     // lane in group: dims [8l, 8l+8)
    int vrow = blockIdx.x * 32 + wid * 8 + g;   // covers ALL NB*1024 perm slots
    int row  = perm[vrow];
    if (row >= NN) return;                   // dummy slots (bucket tail)
    const float inv = 1.0f / 65536.0f;
    int s0  = rp[row];
    int cnt = rp[row + 1] - s0;
    float acc[8] = {0.f, 0.f, 0.f, 0.f, 0.f, 0.f, 0.f, 0.f};
    int gl = g << 3;                         // group's base lane
    int pc = (l < cnt) ? (int)ev[s0 + l] : 0;
    for (int base = 0; base < cnt; base += 8) {
        int nidx = base + 8 + l;
        int pcn = (nidx < cnt) ? (int)ev[s0 + nidx] : 0;   // prefetch next batch
        int pj[8];
        #pragma unroll
        for (int j = 0; j < 8; ++j) pj[j] = __shfl(pc, gl | j);
        half8 xv[8];
        #pragma unroll
        for (int j = 0; j < 8; ++j)
            xv[j] = *(const half8*)(xh + (pj[j] & 0x3FFFF) * 64 + l * 8);  // 16B
        #pragma unroll
        for (int j = 0; j < 8; ++j) {
            float vj = (float)((unsigned)pj[j] >> 18) * inv;
            #pragma unroll
            for (int k = 0; k < 8; ++k)
                acc[k] = fmaf(vj, (float)xv[j][k], acc[k]);
        }
        pc = pcn;
    }
    int o = row * 64 + l * 8;
    if (MODE == 0) {
        half8 st;
        #pragma unroll
        for (int k = 0; k < 8; ++k) st[k] = (half_t)acc[k];
        *(half8*)(yh + o) = st;
    } else {
        const half8 a0 = *(const half8*)(x0h + o);   // X0 (fp16)
        const half8 a1 = *(const half8*)(y1h + o);   // Y1 (fp16)
        const half8 a2 = *(const half8*)(xh + o);    // Y2 (linear read)
        float r[8];
        #pragma unroll
        for (int k = 0; k < 8; ++k)
            r[k] = ((float)a0[k] + (float)a1[k] + (float)a2[k] + acc[k]) * 0.25f;
        *(float4*)(out + o)     = make_float4(r[0], r[1], r[2], r[3]);
        *(float4*)(out + o + 4) = make_float4(r[4], r[5], r[6], r[7]);
    }
}

extern "C" void kernel_launch(void* const* d_in, const int* in_sizes, int n_in,
                              void* d_out, int out_size, void* d_ws, size_t ws_size,
                              hipStream_t stream) {
    const float* ue   = (const float*)d_in[0];
    const float* ie   = (const float*)d_in[1];
    const int*   rows = (const int*)d_in[2];
    const int*   cols = (const int*)d_in[3];
    const float* vals = (const float*)d_in[4];
    float* out = (float*)d_out;

    // Workspace: X0h [XN fp16 = 19.2MB] | Y1h [19.2MB] | Y2h [19.2MB]
    //   (stg aliases Y1h..Y2h: NB*BPC*8B = 28.2MB < 38.4MB, dead before spmm
    //    layer 1 writes Y1h) | ev [E*4 = 9.6MB] | rp [NN+1] | pcnt [NB*16]
    //   | perm [NB*1024].  Total ~69 MB.
    half_t*   X0h   = (half_t*)d_ws;
    half_t*   Y1h   = X0h + XN;
    half_t*   Y2h   = Y1h + XN;
    int2*     stg   = (int2*)Y1h;
    unsigned* ev    = (unsigned*)(Y2h + XN);
    int*      rp    = (int*)(ev + E);
    int*      pcnt  = rp + NN + 4;
    int*      perm  = pcnt + NB * 16;

    (void)hipMemsetAsync(pcnt, 0, NB * 16 * sizeof(int), stream);
    k_pre<<<BGRID + DGRID, BIN_T, 0, stream>>>(rows, cols, vals, stg, pcnt,
                                               ue, ie, X0h);
    k_bsort<<<NB, 1024, 0, stream>>>(stg, pcnt, rp, ev, perm);

    int sgrid = (NB * 1024) / 32;   // 4704 blocks — FULL perm coverage (R13 fix)
    k_spmm<0><<<sgrid, 256, 0, stream>>>(rp, ev, perm, X0h, Y1h, nullptr, nullptr, nullptr); // Y1=A*X0
    k_spmm<0><<<sgrid, 256, 0, stream>>>(rp, ev, perm, Y1h, Y2h, nullptr, nullptr, nullptr); // Y2=A*Y1
    k_spmm<1><<<sgrid, 256, 0, stream>>>(rp, ev, perm, Y2h, nullptr, X0h, Y1h, out);         // combine
}

// Round 7
// 300.551 us; speedup vs baseline: 1.0773x; 1.0773x over previous
//
#include <hip/hip_runtime.h>

// LightGCN: x0 = dropout(concat(user,item)); out = (x0 + A x0 + A^2 x0 + A^3 x0)/4
// R15: revert R13/R14 degree-sort (REGRESSED: masked groups don't issue memory
//   ops, so divergence waste was never the limiter — it cost locality instead:
//   FETCH +10MB, dur 53.8->61). Back to R12 row-adjacent waves, now with a
//   16-wide gather batch: 2 ev code regs, 16 shfls, 16 INDEPENDENT half8
//   gathers issued before the fma block (16 lines in flight per group vs 8).
//   Little's law: R12's 3TB/s @ ~500cy latency matches 8 lines/wave-group x
//   ~13 waves/CU; doubling in-flight should push toward ~4.5TB/s.
//   Pre-registered: positive -> latency-bound confirmed; null -> request-
//   throughput-bound, pivot to preproc.
// fp16 intermediates (R9): gather granule 128B, working set 19.2MB.
// Preproc (R12): dropout fused into k_pre; bscan folded into k_bsort.
// CSR build (R8): two-level counting sort.

static constexpr int NU = 100000;
static constexpr int NI = 50000;
static constexpr int NN = NU + NI;       // 150000
static constexpr int D  = 64;
static constexpr int E  = 2400000;
static constexpr int XN = NN * D;        // 9,600,000
static constexpr int XH = XN / 2;        // 4,800,000
static constexpr int NB = (NN + 1023) >> 10;   // 147 buckets
static constexpr int BPC = 24000;        // bucket staging cap (mean 16327, +59 sigma)
static constexpr int BIN_T = 256;
static constexpr int BIN_U = 16;
static constexpr int BIN_CHUNK = BIN_T * BIN_U;   // 4096
static constexpr int BGRID = (E + BIN_CHUNK - 1) / BIN_CHUNK;   // 586
static constexpr int DGRID = (XH + 255) / 256;                  // 18750

typedef _Float16 half_t;
typedef _Float16 half8 __attribute__((ext_vector_type(8)));

__device__ __forceinline__ unsigned rotl32(unsigned x, int r) {
    return (x << r) | (x >> (32 - r));
}

// Threefry-2x32, 20 rounds (jax_threefry_partitionable=True layout, verified R1).
__device__ __forceinline__ void threefry2x32(unsigned k0, unsigned k1,
                                             unsigned x0, unsigned x1,
                                             unsigned& o0, unsigned& o1) {
    unsigned ks2 = k0 ^ k1 ^ 0x1BD11BDAu;
    x0 += k0; x1 += k1;
#define TF_R(r) { x0 += x1; x1 = rotl32(x1, r); x1 ^= x0; }
    TF_R(13) TF_R(15) TF_R(26) TF_R(6)   x0 += k1;  x1 += ks2 + 1u;
    TF_R(17) TF_R(29) TF_R(16) TF_R(24)  x0 += ks2; x1 += k0 + 2u;
    TF_R(13) TF_R(15) TF_R(26) TF_R(6)   x0 += k0;  x1 += k1 + 3u;
    TF_R(17) TF_R(29) TF_R(16) TF_R(24)  x0 += k1;  x1 += ks2 + 4u;
    TF_R(13) TF_R(15) TF_R(26) TF_R(6)   x0 += ks2; x1 += k0 + 5u;
#undef TF_R
    o0 = x0; o1 = x1;
}

__device__ __forceinline__ float dropout_val(const float* __restrict__ ue,
                                             const float* __restrict__ ie,
                                             int i, unsigned bits) {
    float src = (i < NU * D) ? ue[i] : ie[i - NU * D];
    float u = __uint_as_float((bits >> 9) | 0x3f800000u) - 1.0f;
    return (u < 0.8f) ? (src / 0.8f) : 0.0f;
}

// Fused: blocks [0, BGRID) run the edge-binning pass; blocks [BGRID,
// BGRID+DGRID) run dropout-init. Bin blocks first (critical path to k_bsort);
// dropout streaming overlaps bin's atomic/scatter phase.
__global__ void __launch_bounds__(BIN_T) k_pre(const int* __restrict__ rows,
                                               const int* __restrict__ cols,
                                               const float* __restrict__ vals,
                                               int2* __restrict__ stg,
                                               int* __restrict__ pcnt,
                                               const float* __restrict__ ue,
                                               const float* __restrict__ ie,
                                               half_t* __restrict__ x0h) {
    __shared__ int lcnt[NB];
    __shared__ int gbase[NB];
    int tid = threadIdx.x;
    if (blockIdx.x >= BGRID) {
        // ---- dropout-init body ----
        int j = (blockIdx.x - BGRID) * BIN_T + tid;   // [0, XH)
        if (j >= XH) return;
        unsigned o0, o1, b0, b1;
        threefry2x32(0u, 42u, 0u, (unsigned)j, o0, o1);        b0 = o0 ^ o1;
        threefry2x32(0u, 42u, 0u, (unsigned)(j + XH), o0, o1); b1 = o0 ^ o1;
        x0h[j]      = (half_t)dropout_val(ue, ie, j, b0);
        x0h[j + XH] = (half_t)dropout_val(ue, ie, j + XH, b1);
        return;
    }
    // ---- bin body ----
    for (int i = tid; i < NB; i += BIN_T) lcnt[i] = 0;
    __syncthreads();
    int base = blockIdx.x * BIN_CHUNK;
    int lp[BIN_U];          // (bucket<<13) | loff, or -1 for tail
    int2 rec[BIN_U];
    #pragma unroll
    for (int u = 0; u < BIN_U; ++u) {
        int idx = base + u * BIN_T + tid;
        if (idx < E) {
            int row = rows[idx];
            int col = cols[idx];
            float v = vals[idx];
            unsigned q = min(__float2int_rn(v * 65536.f), 16383);
            int b = row >> 10;
            int loff = atomicAdd(&lcnt[b], 1);
            lp[u] = (b << 13) | loff;               // loff < 4096 < 8192
            rec[u] = make_int2((int)((q << 18) | (unsigned)col), row);
        } else {
            lp[u] = -1;
        }
    }
    __syncthreads();
    for (int i = tid; i < NB; i += BIN_T)
        gbase[i] = atomicAdd(&pcnt[i * 16], lcnt[i]);   // 64B-padded counters
    __syncthreads();
    #pragma unroll
    for (int u = 0; u < BIN_U; ++u) {
        if (lp[u] >= 0) {
            int b = lp[u] >> 13;
            int pos = gbase[b] + (lp[u] & 8191);
            if (pos < BPC) stg[(size_t)b * BPC + pos] = rec[u];
        }
    }
}

// One block per bucket. Wave 0 computes this bucket's global base (redundant
// 147-prefix, replaces k_bscan). Then: LDS hist of 1024 rows, block scan,
// write rp, scatter records into the bucket's dense [bb, bb+tot) ev region.
__global__ void __launch_bounds__(1024) k_bsort(const int2* __restrict__ stg,
                                                const int* __restrict__ pcnt,
                                                int* __restrict__ rp,
                                                unsigned* __restrict__ ev) {
    __shared__ int cnt[1024];
    __shared__ int wsum[16];
    __shared__ int sbb;
    int b = blockIdx.x;
    int t = threadIdx.x;
    cnt[t] = 0;
    if (t < 64) {
        // exclusive prefix over buckets < b (one wave, <=3 values/lane)
        int a = 0;
        for (int i = t; i < b; i += 64) a += pcnt[i * 16];
        #pragma unroll
        for (int d = 1; d < 64; d <<= 1) a += __shfl_xor(a, d);
        if (t == 0) sbb = a;
    }
    if (b == 0 && t == 0) rp[NN] = E;    // sentinel
    __syncthreads();
    int tot = min(pcnt[b * 16], BPC);
    int bb = sbb;
    const int2* s = stg + (size_t)b * BPC;
    for (int i = t; i < tot; i += 1024)
        atomicAdd(&cnt[s[i].y & 1023], 1);
    __syncthreads();
    // Block-wide exclusive scan of cnt[1024].
    int v = cnt[t];
    int lane = t & 63, w = t >> 6;
    int x = v;
    #pragma unroll
    for (int d = 1; d < 64; d <<= 1) {
        int y = __shfl_up(x, d);
        if (lane >= d) x += y;
    }
    if (lane == 63) wsum[w] = x;
    __syncthreads();
    if (w == 0 && lane < 16) {
        int sv = wsum[lane];
        #pragma unroll
        for (int d = 1; d < 16; d <<= 1) {
            int y = __shfl_up(sv, d);
            if (lane >= d) sv += y;
        }
        wsum[lane] = sv;
    }
    __syncthreads();
    int excl = ((w > 0) ? wsum[w - 1] : 0) + x - v;
    int row = (b << 10) + t;
    if (row < NN) rp[row] = bb + excl;
    __syncthreads();
    cnt[t] = bb + excl;               // becomes the scatter cursor
    __syncthreads();
    for (int i = t; i < tot; i += 1024) {
        int2 r = s[i];
        int pos = atomicAdd(&cnt[r.y & 1023], 1);
        ev[pos] = (unsigned)r.x;
    }
}

// Pull SpMM over exact CSR, fp16 x. Wave = 8 adjacent rows; 8-lane group owns
// a row (lane l holds dims [8l,8l+8), 16B). 16-edge batch: two code regs,
// 16 shfl broadcasts, 16 INDEPENDENT half8 gathers issued before the fma
// block (16 lines in flight per group), 2-deep ev prefetch.
// Padded edges (idx>=cnt) have code 0 -> v=0, gather x[0] (L1-hot), harmless.
// MODE 0: yh = A*xh (fp16 out). MODE 1: out_f32 = (x0h + y1h + xh + A*xh)*0.25.
template <int MODE>
__global__ void __launch_bounds__(256) k_spmm(const int* __restrict__ rp,
                                              const unsigned* __restrict__ ev,
                                              const half_t* __restrict__ xh,
                                              half_t* __restrict__ yh,
                                              const half_t* __restrict__ x0h,
                                              const half_t* __restrict__ y1h,
                                              float* __restrict__ out) {
    int wid  = threadIdx.x >> 6;             // wave in block: 0..3
    int lane = threadIdx.x & 63;
    int g    = lane >> 3;                    // group (row slot) 0..7
    int l    = lane & 7;                     // lane in group: dims [8l, 8l+8)
    int row  = blockIdx.x * 32 + wid * 8 + g;
    if (row >= NN) return;
    const float inv = 1.0f / 65536.0f;
    int s0  = rp[row];
    int cnt = rp[row + 1] - s0;
    float acc[8] = {0.f, 0.f, 0.f, 0.f, 0.f, 0.f, 0.f, 0.f};
    int gl = g << 3;                         // group's base lane
    int pc0 = (l < cnt)     ? (int)ev[s0 + l] : 0;
    int pc1 = (8 + l < cnt) ? (int)ev[s0 + 8 + l] : 0;
    for (int base = 0; base < cnt; base += 16) {
        int n0 = base + 16 + l;
        int n1 = base + 24 + l;
        int pn0 = (n0 < cnt) ? (int)ev[s0 + n0] : 0;   // prefetch next batch
        int pn1 = (n1 < cnt) ? (int)ev[s0 + n1] : 0;
        int pj[16];
        #pragma unroll
        for (int j = 0; j < 8; ++j) {
            pj[j]     = __shfl(pc0, gl | j);
            pj[8 + j] = __shfl(pc1, gl | j);
        }
        half8 xv[16];
        #pragma unroll
        for (int j = 0; j < 16; ++j)
            xv[j] = *(const half8*)(xh + (pj[j] & 0x3FFFF) * 64 + l * 8);  // 16B
        #pragma unroll
        for (int j = 0; j < 16; ++j) {
            float vj = (float)((unsigned)pj[j] >> 18) * inv;
            #pragma unroll
            for (int k = 0; k < 8; ++k)
                acc[k] = fmaf(vj, (float)xv[j][k], acc[k]);
        }
        pc0 = pn0;
        pc1 = pn1;
    }
    int o = row * 64 + l * 8;
    if (MODE == 0) {
        half8 st;
        #pragma unroll
        for (int k = 0; k < 8; ++k) st[k] = (half_t)acc[k];
        *(half8*)(yh + o) = st;
    } else {
        const half8 a0 = *(const half8*)(x0h + o);   // X0 (fp16)
        const half8 a1 = *(const half8*)(y1h + o);   // Y1 (fp16)
        const half8 a2 = *(const half8*)(xh + o);    // Y2 (linear read)
        float r[8];
        #pragma unroll
        for (int k = 0; k < 8; ++k)
            r[k] = ((float)a0[k] + (float)a1[k] + (float)a2[k] + acc[k]) * 0.25f;
        *(float4*)(out + o)     = make_float4(r[0], r[1], r[2], r[3]);
        *(float4*)(out + o + 4) = make_float4(r[4], r[5], r[6], r[7]);
    }
}

extern "C" void kernel_launch(void* const* d_in, const int* in_sizes, int n_in,
                              void* d_out, int out_size, void* d_ws, size_t ws_size,
                              hipStream_t stream) {
    const float* ue   = (const float*)d_in[0];
    const float* ie   = (const float*)d_in[1];
    const int*   rows = (const int*)d_in[2];
    const int*   cols = (const int*)d_in[3];
    const float* vals = (const float*)d_in[4];
    float* out = (float*)d_out;

    // Workspace: X0h [XN fp16 = 19.2MB] | Y1h [19.2MB] | Y2h [19.2MB]
    //   (stg aliases Y1h..Y2h: NB*BPC*8B = 28.2MB < 38.4MB, dead before spmm
    //    layer 1 writes Y1h) | ev [E*4 = 9.6MB] | rp [NN+1] | pcnt [NB*16].
    //   Total ~68 MB.
    half_t*   X0h   = (half_t*)d_ws;
    half_t*   Y1h   = X0h + XN;
    half_t*   Y2h   = Y1h + XN;
    int2*     stg   = (int2*)Y1h;
    unsigned* ev    = (unsigned*)(Y2h + XN);
    int*      rp    = (int*)(ev + E);
    int*      pcnt  = rp + NN + 4;

    (void)hipMemsetAsync(pcnt, 0, NB * 16 * sizeof(int), stream);
    k_pre<<<BGRID + DGRID, BIN_T, 0, stream>>>(rows, cols, vals, stg, pcnt,
                                               ue, ie, X0h);
    k_bsort<<<NB, 1024, 0, stream>>>(stg, pcnt, rp, ev);

    int sgrid = (NN + 31) / 32;   // 32 rows per block (4 waves x 8 rows)
    k_spmm<0><<<sgrid, 256, 0, stream>>>(rp, ev, X0h, Y1h, nullptr, nullptr, nullptr); // Y1=A*X0
    k_spmm<0><<<sgrid, 256, 0, stream>>>(rp, ev, Y1h, Y2h, nullptr, nullptr, nullptr); // Y2=A*Y1
    k_spmm<1><<<sgrid, 256, 0, stream>>>(rp, ev, Y2h, nullptr, X0h, Y1h, out);         // combine
}

// Round 8
// 290.392 us; speedup vs baseline: 1.1150x; 1.0350x over previous
//
#include <hip/hip_runtime.h>

// LightGCN: x0 = dropout(concat(user,item)); out = (x0 + A x0 + A^2 x0 + A^3 x0)/4
// R16: preprocessing-tail fixes (spmm kept from R15: 52.7-52.9us).
//   R15 post-mortem: VGPR 48->40 proves the compiler COLLAPSED the 16-wide
//   gather batch (source-level MLP widening is defeated; forcing needs asm
//   + counted vmcnt — deferred). Accounting: 3 spmm ~158us + k_pre 52.9us
//   leaves ~90us in k_bsort + overhead. k_bsort = 147 blocks (1/CU, no TLP),
//   TWO passes over stg, ~48 lines in flight -> HBM-latency-bound ~35-40us.
//   Fixes:
//   (1) k_bsort: single-pass — 24 records/thread loaded into REGISTERS
//       up-front (24 independent loads/lane in flight), hist/scatter from
//       regs. Second stg read deleted.
//   (2) k_pre: bin loads edges as int4/float4 (4 edges/load, batched);
//       dropout handles 8 contiguous elems/thread (2x float4 in, half8 out,
//       8 independent threefry chains). Same absolute-index PRNG -> bit-
//       identical output. NU*D & E divisible by 8 -> no straddle.
// fp16 intermediates (R9): gather granule 128B, working set 19.2MB.
// CSR build (R8): two-level counting sort. SpMM (R11/R15): wave = 8 adjacent
// rows, 8-lane group per row, 16-edge batch, 2-deep ev prefetch.

static constexpr int NU = 100000;
static constexpr int NI = 50000;
static constexpr int NN = NU + NI;       // 150000
static constexpr int D  = 64;
static constexpr int E  = 2400000;
static constexpr int XN = NN * D;        // 9,600,000
static constexpr int NUD = NU * D;       // 6,400,000 (div by 8)
static constexpr int NB = (NN + 1023) >> 10;   // 147 buckets
static constexpr int BPC = 24000;        // bucket staging cap (mean 16327, +59 sigma)
static constexpr int BIN_T = 256;
static constexpr int BIN_U = 16;
static constexpr int BIN_CHUNK = BIN_T * BIN_U;   // 4096
static constexpr int BGRID = (E + BIN_CHUNK - 1) / BIN_CHUNK;   // 586
static constexpr int DGRID = (XN / 8 + BIN_T - 1) / BIN_T;      // 4688
static constexpr int RPT = 24;           // k_bsort records per thread (24*1024 >= BPC)

typedef _Float16 half_t;
typedef _Float16 half8 __attribute__((ext_vector_type(8)));

__device__ __forceinline__ unsigned rotl32(unsigned x, int r) {
    return (x << r) | (x >> (32 - r));
}

// Threefry-2x32, 20 rounds (jax_threefry_partitionable=True layout, verified R1).
__device__ __forceinline__ void threefry2x32(unsigned k0, unsigned k1,
                                             unsigned x0, unsigned x1,
                                             unsigned& o0, unsigned& o1) {
    unsigned ks2 = k0 ^ k1 ^ 0x1BD11BDAu;
    x0 += k0; x1 += k1;
#define TF_R(r) { x0 += x1; x1 = rotl32(x1, r); x1 ^= x0; }
    TF_R(13) TF_R(15) TF_R(26) TF_R(6)   x0 += k1;  x1 += ks2 + 1u;
    TF_R(17) TF_R(29) TF_R(16) TF_R(24)  x0 += ks2; x1 += k0 + 2u;
    TF_R(13) TF_R(15) TF_R(26) TF_R(6)   x0 += k0;  x1 += k1 + 3u;
    TF_R(17) TF_R(29) TF_R(16) TF_R(24)  x0 += k1;  x1 += ks2 + 4u;
    TF_R(13) TF_R(15) TF_R(26) TF_R(6)   x0 += ks2; x1 += k0 + 5u;
#undef TF_R
    o0 = x0; o1 = x1;
}

// Fused preproc. Blocks [0, BGRID): edge binning. Blocks [BGRID, +DGRID):
// dropout-init, 8 contiguous elements per thread.
__global__ void __launch_bounds__(BIN_T) k_pre(const int* __restrict__ rows,
                                               const int* __restrict__ cols,
                                               const float* __restrict__ vals,
                                               int2* __restrict__ stg,
                                               int* __restrict__ pcnt,
                                               const float* __restrict__ ue,
                                               const float* __restrict__ ie,
                                               half_t* __restrict__ x0h) {
    __shared__ int lcnt[NB];
    __shared__ int gbase[NB];
    int tid = threadIdx.x;
    if (blockIdx.x >= BGRID) {
        // ---- dropout-init: 8 elems/thread, vectorized ----
        int j8 = (blockIdx.x - BGRID) * BIN_T + tid;
        if (j8 >= XN / 8) return;
        int j0 = j8 * 8;
        // NUD % 8 == 0 -> chunk never straddles the ue/ie boundary.
        const float* src = (j0 < NUD) ? (ue + j0) : (ie + (j0 - NUD));
        float4 f0 = *(const float4*)(src);
        float4 f1 = *(const float4*)(src + 4);
        float f[8] = {f0.x, f0.y, f0.z, f0.w, f1.x, f1.y, f1.z, f1.w};
        half8 st;
        #pragma unroll
        for (int k = 0; k < 8; ++k) {
            unsigned o0, o1;
            threefry2x32(0u, 42u, 0u, (unsigned)(j0 + k), o0, o1);
            unsigned bits = o0 ^ o1;
            float u = __uint_as_float((bits >> 9) | 0x3f800000u) - 1.0f;
            st[k] = (half_t)((u < 0.8f) ? f[k] * 1.25f : 0.0f);
        }
        *(half8*)(x0h + j0) = st;
        return;
    }
    // ---- bin body: 16 edges/thread via 4x int4/float4 vector loads ----
    for (int i = tid; i < NB; i += BIN_T) lcnt[i] = 0;
    __syncthreads();
    int base = blockIdx.x * BIN_CHUNK;
    int lp[BIN_U];          // (bucket<<13) | loff, or -1 for tail
    int2 rec[BIN_U];
    int4  r4[4], c4[4];
    float4 v4[4];
    #pragma unroll
    for (int u4 = 0; u4 < 4; ++u4) {
        int e0 = base + (u4 * BIN_T + tid) * 4;   // E%4==0: all-in or all-out
        if (e0 < E) {
            r4[u4] = *(const int4*)(rows + e0);
            c4[u4] = *(const int4*)(cols + e0);
            v4[u4] = *(const float4*)(vals + e0);
        }
    }
    #pragma unroll
    for (int u4 = 0; u4 < 4; ++u4) {
        int e0 = base + (u4 * BIN_T + tid) * 4;
        int rr[4] = {r4[u4].x, r4[u4].y, r4[u4].z, r4[u4].w};
        int cc[4] = {c4[u4].x, c4[u4].y, c4[u4].z, c4[u4].w};
        float vv[4] = {v4[u4].x, v4[u4].y, v4[u4].z, v4[u4].w};
        #pragma unroll
        for (int k = 0; k < 4; ++k) {
            int u = u4 * 4 + k;
            if (e0 < E) {
                unsigned q = min(__float2int_rn(vv[k] * 65536.f), 16383);
                int b = rr[k] >> 10;
                int loff = atomicAdd(&lcnt[b], 1);
                lp[u] = (b << 13) | loff;           // loff < 4096 < 8192
                rec[u] = make_int2((int)((q << 18) | (unsigned)cc[k]), rr[k]);
            } else {
                lp[u] = -1;
            }
        }
    }
    __syncthreads();
    for (int i = tid; i < NB; i += BIN_T)
        gbase[i] = atomicAdd(&pcnt[i * 16], lcnt[i]);   // 64B-padded counters
    __syncthreads();
    #pragma unroll
    for (int u = 0; u < BIN_U; ++u) {
        if (lp[u] >= 0) {
            int b = lp[u] >> 13;
            int pos = gbase[b] + (lp[u] & 8191);
            if (pos < BPC) stg[(size_t)b * BPC + pos] = rec[u];
        }
    }
}

// One block per bucket, SINGLE pass over stg: up to 24 records/thread loaded
// into registers up-front (24 independent 8B loads in flight per lane ->
// latency hidden even at 1 block/CU). Wave 0 computes the bucket's global
// base (replaces k_bscan). Then LDS hist from regs, block scan -> rp, and
// scatter from regs into the bucket's dense ev region.
__global__ void __launch_bounds__(1024) k_bsort(const int2* __restrict__ stg,
                                                const int* __restrict__ pcnt,
                                                int* __restrict__ rp,
                                                unsigned* __restrict__ ev) {
    __shared__ int cnt[1024];
    __shared__ int wsum[16];
    __shared__ int sbb;
    int b = blockIdx.x;
    int t = threadIdx.x;
    cnt[t] = 0;
    if (t < 64) {
        // exclusive prefix over buckets < b (one wave, <=3 values/lane)
        int a = 0;
        for (int i = t; i < b; i += 64) a += pcnt[i * 16];
        #pragma unroll
        for (int d = 1; d < 64; d <<= 1) a += __shfl_xor(a, d);
        if (t == 0) sbb = a;
    }
    if (b == 0 && t == 0) rp[NN] = E;    // sentinel
    __syncthreads();
    int tot = min(pcnt[b * 16], BPC);
    int bb = sbb;
    const int2* s = stg + (size_t)b * BPC;
    // Batched register load of this thread's records (independent loads).
    int2 rec[RPT];
    #pragma unroll
    for (int u = 0; u < RPT; ++u) {
        int i = t + u * 1024;
        if (i < tot) rec[u] = s[i];
    }
    #pragma unroll
    for (int u = 0; u < RPT; ++u) {
        int i = t + u * 1024;
        if (i < tot) atomicAdd(&cnt[rec[u].y & 1023], 1);
    }
    __syncthreads();
    // Block-wide exclusive scan of cnt[1024].
    int v = cnt[t];
    int lane = t & 63, w = t >> 6;
    int x = v;
    #pragma unroll
    for (int d = 1; d < 64; d <<= 1) {
        int y = __shfl_up(x, d);
        if (lane >= d) x += y;
    }
    if (lane == 63) wsum[w] = x;
    __syncthreads();
    if (w == 0 && lane < 16) {
        int sv = wsum[lane];
        #pragma unroll
        for (int d = 1; d < 16; d <<= 1) {
            int y = __shfl_up(sv, d);
            if (lane >= d) sv += y;
        }
        wsum[lane] = sv;
    }
    __syncthreads();
    int excl = ((w > 0) ? wsum[w - 1] : 0) + x - v;
    int row = (b << 10) + t;
    if (row < NN) rp[row] = bb + excl;
    __syncthreads();
    cnt[t] = bb + excl;               // becomes the scatter cursor
    __syncthreads();
    #pragma unroll
    for (int u = 0; u < RPT; ++u) {
        int i = t + u * 1024;
        if (i < tot) {
            int pos = atomicAdd(&cnt[rec[u].y & 1023], 1);
            ev[pos] = (unsigned)rec[u].x;
        }
    }
}

// Pull SpMM over exact CSR, fp16 x (R15, unchanged: 52.7-52.9us measured).
// Wave = 8 adjacent rows; 8-lane group owns a row (lane l = dims [8l,8l+8)).
// 16-edge batch, 2-deep ev prefetch.
// MODE 0: yh = A*xh (fp16 out). MODE 1: out_f32 = (x0h + y1h + xh + A*xh)*0.25.
template <int MODE>
__global__ void __launch_bounds__(256) k_spmm(const int* __restrict__ rp,
                                              const unsigned* __restrict__ ev,
                                              const half_t* __restrict__ xh,
                                              half_t* __restrict__ yh,
                                              const half_t* __restrict__ x0h,
                                              const half_t* __restrict__ y1h,
                                              float* __restrict__ out) {
    int wid  = threadIdx.x >> 6;             // wave in block: 0..3
    int lane = threadIdx.x & 63;
    int g    = lane >> 3;                    // group (row slot) 0..7
    int l    = lane & 7;                     // lane in group: dims [8l, 8l+8)
    int row  = blockIdx.x * 32 + wid * 8 + g;
    if (row >= NN) return;
    const float inv = 1.0f / 65536.0f;
    int s0  = rp[row];
    int cnt = rp[row + 1] - s0;
    float acc[8] = {0.f, 0.f, 0.f, 0.f, 0.f, 0.f, 0.f, 0.f};
    int gl = g << 3;                         // group's base lane
    int pc0 = (l < cnt)     ? (int)ev[s0 + l] : 0;
    int pc1 = (8 + l < cnt) ? (int)ev[s0 + 8 + l] : 0;
    for (int base = 0; base < cnt; base += 16) {
        int n0 = base + 16 + l;
        int n1 = base + 24 + l;
        int pn0 = (n0 < cnt) ? (int)ev[s0 + n0] : 0;   // prefetch next batch
        int pn1 = (n1 < cnt) ? (int)ev[s0 + n1] : 0;
        int pj[16];
        #pragma unroll
        for (int j = 0; j < 8; ++j) {
            pj[j]     = __shfl(pc0, gl | j);
            pj[8 + j] = __shfl(pc1, gl | j);
        }
        half8 xv[16];
        #pragma unroll
        for (int j = 0; j < 16; ++j)
            xv[j] = *(const half8*)(xh + (pj[j] & 0x3FFFF) * 64 + l * 8);  // 16B
        #pragma unroll
        for (int j = 0; j < 16; ++j) {
            float vj = (float)((unsigned)pj[j] >> 18) * inv;
            #pragma unroll
            for (int k = 0; k < 8; ++k)
                acc[k] = fmaf(vj, (float)xv[j][k], acc[k]);
        }
        pc0 = pn0;
        pc1 = pn1;
    }
    int o = row * 64 + l * 8;
    if (MODE == 0) {
        half8 st;
        #pragma unroll
        for (int k = 0; k < 8; ++k) st[k] = (half_t)acc[k];
        *(half8*)(yh + o) = st;
    } else {
        const half8 a0 = *(const half8*)(x0h + o);   // X0 (fp16)
        const half8 a1 = *(const half8*)(y1h + o);   // Y1 (fp16)
        const half8 a2 = *(const half8*)(xh + o);    // Y2 (linear read)
        float r[8];
        #pragma unroll
        for (int k = 0; k < 8; ++k)
            r[k] = ((float)a0[k] + (float)a1[k] + (float)a2[k] + acc[k]) * 0.25f;
        *(float4*)(out + o)     = make_float4(r[0], r[1], r[2], r[3]);
        *(float4*)(out + o + 4) = make_float4(r[4], r[5], r[6], r[7]);
    }
}

extern "C" void kernel_launch(void* const* d_in, const int* in_sizes, int n_in,
                              void* d_out, int out_size, void* d_ws, size_t ws_size,
                              hipStream_t stream) {
    const float* ue   = (const float*)d_in[0];
    const float* ie   = (const float*)d_in[1];
    const int*   rows = (const int*)d_in[2];
    const int*   cols = (const int*)d_in[3];
    const float* vals = (const float*)d_in[4];
    float* out = (float*)d_out;

    // Workspace: X0h [XN fp16 = 19.2MB] | Y1h [19.2MB] | Y2h [19.2MB]
    //   (stg aliases Y1h..Y2h: NB*BPC*8B = 28.2MB < 38.4MB, dead before spmm
    //    layer 1 writes Y1h) | ev [E*4 = 9.6MB] | rp [NN+1] | pcnt [NB*16].
    //   Total ~68 MB.
    half_t*   X0h   = (half_t*)d_ws;
    half_t*   Y1h   = X0h + XN;
    half_t*   Y2h   = Y1h + XN;
    int2*     stg   = (int2*)Y1h;
    unsigned* ev    = (unsigned*)(Y2h + XN);
    int*      rp    = (int*)(ev + E);
    int*      pcnt  = rp + NN + 4;

    (void)hipMemsetAsync(pcnt, 0, NB * 16 * sizeof(int), stream);
    k_pre<<<BGRID + DGRID, BIN_T, 0, stream>>>(rows, cols, vals, stg, pcnt,
                                               ue, ie, X0h);
    k_bsort<<<NB, 1024, 0, stream>>>(stg, pcnt, rp, ev);

    int sgrid = (NN + 31) / 32;   // 32 rows per block (4 waves x 8 rows)
    k_spmm<0><<<sgrid, 256, 0, stream>>>(rp, ev, X0h, Y1h, nullptr, nullptr, nullptr); // Y1=A*X0
    k_spmm<0><<<sgrid, 256, 0, stream>>>(rp, ev, Y1h, Y2h, nullptr, nullptr, nullptr); // Y2=A*Y1
    k_spmm<1><<<sgrid, 256, 0, stream>>>(rp, ev, Y2h, nullptr, X0h, Y1h, out);         // combine
}

// Round 9
// 288.548 us; speedup vs baseline: 1.1221x; 1.0064x over previous
//
#include <hip/hip_runtime.h>

// LightGCN: x0 = dropout(concat(user,item)); out = (x0 + A x0 + A^2 x0 + A^3 x0)/4
// R17: asm-forced 16-deep gather batch in spmm.
//   R15 showed the compiler collapses source-level MLP widening (VGPR 48->40,
//   dur flat). Force it: 16 global_load_dwordx4 issued via inline asm (saddr
//   form: xh in SGPR, 32-bit voffset), ALL outputs live before one explicit
//   s_waitcnt vmcnt(0) + sched_barrier(0) (rule #18: the sched_barrier after
//   the wait is the real fence — "memory" doesn't order register-only fmas).
//   Per wave: 16 instr x 8 lines = 128 lines in flight vs ~20 before. Most
//   rows have cnt<=16 -> one batch/row, so the per-batch drain is ~per-row.
//   Pre-registered: VGPR must jump to ~96-128 (else forcing failed/void);
//   dur 52.7->~42 confirms latency-bound; dur flat with VGPR up => request-
//   throughput bound, spmm declared done.
// fp16 intermediates (R9): gather granule 128B, working set 19.2MB.
// Preproc (R16): vectorized fused k_pre; single-pass register k_bsort.
// CSR build (R8): two-level counting sort. SpMM decomposition (R11): wave =
// 8 adjacent rows, 8-lane group per row.

static constexpr int NU = 100000;
static constexpr int NI = 50000;
static constexpr int NN = NU + NI;       // 150000
static constexpr int D  = 64;
static constexpr int E  = 2400000;
static constexpr int XN = NN * D;        // 9,600,000
static constexpr int NUD = NU * D;       // 6,400,000 (div by 8)
static constexpr int NB = (NN + 1023) >> 10;   // 147 buckets
static constexpr int BPC = 24000;        // bucket staging cap (mean 16327, +59 sigma)
static constexpr int BIN_T = 256;
static constexpr int BIN_U = 16;
static constexpr int BIN_CHUNK = BIN_T * BIN_U;   // 4096
static constexpr int BGRID = (E + BIN_CHUNK - 1) / BIN_CHUNK;   // 586
static constexpr int DGRID = (XN / 8 + BIN_T - 1) / BIN_T;      // 4688
static constexpr int RPT = 24;           // k_bsort records per thread (24*1024 >= BPC)

typedef _Float16 half_t;
typedef _Float16 half8 __attribute__((ext_vector_type(8)));

__device__ __forceinline__ unsigned rotl32(unsigned x, int r) {
    return (x << r) | (x >> (32 - r));
}

// Threefry-2x32, 20 rounds (jax_threefry_partitionable=True layout, verified R1).
__device__ __forceinline__ void threefry2x32(unsigned k0, unsigned k1,
                                             unsigned x0, unsigned x1,
                                             unsigned& o0, unsigned& o1) {
    unsigned ks2 = k0 ^ k1 ^ 0x1BD11BDAu;
    x0 += k0; x1 += k1;
#define TF_R(r) { x0 += x1; x1 = rotl32(x1, r); x1 ^= x0; }
    TF_R(13) TF_R(15) TF_R(26) TF_R(6)   x0 += k1;  x1 += ks2 + 1u;
    TF_R(17) TF_R(29) TF_R(16) TF_R(24)  x0 += ks2; x1 += k0 + 2u;
    TF_R(13) TF_R(15) TF_R(26) TF_R(6)   x0 += k0;  x1 += k1 + 3u;
    TF_R(17) TF_R(29) TF_R(16) TF_R(24)  x0 += k1;  x1 += ks2 + 4u;
    TF_R(13) TF_R(15) TF_R(26) TF_R(6)   x0 += ks2; x1 += k0 + 5u;
#undef TF_R
    o0 = x0; o1 = x1;
}

// Fused preproc. Blocks [0, BGRID): edge binning. Blocks [BGRID, +DGRID):
// dropout-init, 8 contiguous elements per thread.
__global__ void __launch_bounds__(BIN_T) k_pre(const int* __restrict__ rows,
                                               const int* __restrict__ cols,
                                               const float* __restrict__ vals,
                                               int2* __restrict__ stg,
                                               int* __restrict__ pcnt,
                                               const float* __restrict__ ue,
                                               const float* __restrict__ ie,
                                               half_t* __restrict__ x0h) {
    __shared__ int lcnt[NB];
    __shared__ int gbase[NB];
    int tid = threadIdx.x;
    if (blockIdx.x >= BGRID) {
        // ---- dropout-init: 8 elems/thread, vectorized ----
        int j8 = (blockIdx.x - BGRID) * BIN_T + tid;
        if (j8 >= XN / 8) return;
        int j0 = j8 * 8;
        // NUD % 8 == 0 -> chunk never straddles the ue/ie boundary.
        const float* src = (j0 < NUD) ? (ue + j0) : (ie + (j0 - NUD));
        float4 f0 = *(const float4*)(src);
        float4 f1 = *(const float4*)(src + 4);
        float f[8] = {f0.x, f0.y, f0.z, f0.w, f1.x, f1.y, f1.z, f1.w};
        half8 st;
        #pragma unroll
        for (int k = 0; k < 8; ++k) {
            unsigned o0, o1;
            threefry2x32(0u, 42u, 0u, (unsigned)(j0 + k), o0, o1);
            unsigned bits = o0 ^ o1;
            float u = __uint_as_float((bits >> 9) | 0x3f800000u) - 1.0f;
            st[k] = (half_t)((u < 0.8f) ? f[k] * 1.25f : 0.0f);
        }
        *(half8*)(x0h + j0) = st;
        return;
    }
    // ---- bin body: 16 edges/thread via 4x int4/float4 vector loads ----
    for (int i = tid; i < NB; i += BIN_T) lcnt[i] = 0;
    __syncthreads();
    int base = blockIdx.x * BIN_CHUNK;
    int lp[BIN_U];          // (bucket<<13) | loff, or -1 for tail
    int2 rec[BIN_U];
    int4  r4[4], c4[4];
    float4 v4[4];
    #pragma unroll
    for (int u4 = 0; u4 < 4; ++u4) {
        int e0 = base + (u4 * BIN_T + tid) * 4;   // E%4==0: all-in or all-out
        if (e0 < E) {
            r4[u4] = *(const int4*)(rows + e0);
            c4[u4] = *(const int4*)(cols + e0);
            v4[u4] = *(const float4*)(vals + e0);
        }
    }
    #pragma unroll
    for (int u4 = 0; u4 < 4; ++u4) {
        int e0 = base + (u4 * BIN_T + tid) * 4;
        int rr[4] = {r4[u4].x, r4[u4].y, r4[u4].z, r4[u4].w};
        int cc[4] = {c4[u4].x, c4[u4].y, c4[u4].z, c4[u4].w};
        float vv[4] = {v4[u4].x, v4[u4].y, v4[u4].z, v4[u4].w};
        #pragma unroll
        for (int k = 0; k < 4; ++k) {
            int u = u4 * 4 + k;
            if (e0 < E) {
                unsigned q = min(__float2int_rn(vv[k] * 65536.f), 16383);
                int b = rr[k] >> 10;
                int loff = atomicAdd(&lcnt[b], 1);
                lp[u] = (b << 13) | loff;           // loff < 4096 < 8192
                rec[u] = make_int2((int)((q << 18) | (unsigned)cc[k]), rr[k]);
            } else {
                lp[u] = -1;
            }
        }
    }
    __syncthreads();
    for (int i = tid; i < NB; i += BIN_T)
        gbase[i] = atomicAdd(&pcnt[i * 16], lcnt[i]);   // 64B-padded counters
    __syncthreads();
    #pragma unroll
    for (int u = 0; u < BIN_U; ++u) {
        if (lp[u] >= 0) {
            int b = lp[u] >> 13;
            int pos = gbase[b] + (lp[u] & 8191);
            if (pos < BPC) stg[(size_t)b * BPC + pos] = rec[u];
        }
    }
}

// One block per bucket, SINGLE pass over stg: up to 24 records/thread loaded
// into registers up-front (24 independent 8B loads in flight per lane).
// Wave 0 computes the bucket's global base (replaces k_bscan). Then LDS hist
// from regs, block scan -> rp, scatter from regs into the dense ev region.
__global__ void __launch_bounds__(1024) k_bsort(const int2* __restrict__ stg,
                                                const int* __restrict__ pcnt,
                                                int* __restrict__ rp,
                                                unsigned* __restrict__ ev) {
    __shared__ int cnt[1024];
    __shared__ int wsum[16];
    __shared__ int sbb;
    int b = blockIdx.x;
    int t = threadIdx.x;
    cnt[t] = 0;
    if (t < 64) {
        // exclusive prefix over buckets < b (one wave, <=3 values/lane)
        int a = 0;
        for (int i = t; i < b; i += 64) a += pcnt[i * 16];
        #pragma unroll
        for (int d = 1; d < 64; d <<= 1) a += __shfl_xor(a, d);
        if (t == 0) sbb = a;
    }
    if (b == 0 && t == 0) rp[NN] = E;    // sentinel
    __syncthreads();
    int tot = min(pcnt[b * 16], BPC);
    int bb = sbb;
    const int2* s = stg + (size_t)b * BPC;
    // Batched register load of this thread's records (independent loads).
    int2 rec[RPT];
    #pragma unroll
    for (int u = 0; u < RPT; ++u) {
        int i = t + u * 1024;
        if (i < tot) rec[u] = s[i];
    }
    #pragma unroll
    for (int u = 0; u < RPT; ++u) {
        int i = t + u * 1024;
        if (i < tot) atomicAdd(&cnt[rec[u].y & 1023], 1);
    }
    __syncthreads();
    // Block-wide exclusive scan of cnt[1024].
    int v = cnt[t];
    int lane = t & 63, w = t >> 6;
    int x = v;
    #pragma unroll
    for (int d = 1; d < 64; d <<= 1) {
        int y = __shfl_up(x, d);
        if (lane >= d) x += y;
    }
    if (lane == 63) wsum[w] = x;
    __syncthreads();
    if (w == 0 && lane < 16) {
        int sv = wsum[lane];
        #pragma unroll
        for (int d = 1; d < 16; d <<= 1) {
            int y = __shfl_up(sv, d);
            if (lane >= d) sv += y;
        }
        wsum[lane] = sv;
    }
    __syncthreads();
    int excl = ((w > 0) ? wsum[w - 1] : 0) + x - v;
    int row = (b << 10) + t;
    if (row < NN) rp[row] = bb + excl;
    __syncthreads();
    cnt[t] = bb + excl;               // becomes the scatter cursor
    __syncthreads();
    #pragma unroll
    for (int u = 0; u < RPT; ++u) {
        int i = t + u * 1024;
        if (i < tot) {
            int pos = atomicAdd(&cnt[rec[u].y & 1023], 1);
            ev[pos] = (unsigned)rec[u].x;
        }
    }
}

// Pull SpMM over exact CSR, fp16 x. Wave = 8 adjacent rows; 8-lane group owns
// a row (lane l holds dims [8l,8l+8), 16B). 16-edge batch with ASM-FORCED
// MLP: 16 global_load_dwordx4 (saddr form) issued back-to-back, all outputs
// live, one s_waitcnt vmcnt(0) + sched_barrier(0), then the fma block.
// Padded edges (idx>=cnt) have code 0 -> v=0, gather x[0] (L1-hot), harmless.
// MODE 0: yh = A*xh (fp16 out). MODE 1: out_f32 = (x0h + y1h + xh + A*xh)*0.25.
template <int MODE>
__global__ void __launch_bounds__(256) k_spmm(const int* __restrict__ rp,
                                              const unsigned* __restrict__ ev,
                                              const half_t* __restrict__ xh,
                                              half_t* __restrict__ yh,
                                              const half_t* __restrict__ x0h,
                                              const half_t* __restrict__ y1h,
                                              float* __restrict__ out) {
    int wid  = threadIdx.x >> 6;             // wave in block: 0..3
    int lane = threadIdx.x & 63;
    int g    = lane >> 3;                    // group (row slot) 0..7
    int l    = lane & 7;                     // lane in group: dims [8l, 8l+8)
    int row  = blockIdx.x * 32 + wid * 8 + g;
    if (row >= NN) return;
    const float inv = 1.0f / 65536.0f;
    int s0  = rp[row];
    int cnt = rp[row + 1] - s0;
    float acc[8] = {0.f, 0.f, 0.f, 0.f, 0.f, 0.f, 0.f, 0.f};
    int gl = g << 3;                         // group's base lane
    int lb = l * 16;                         // lane's byte offset within a row
    int pc0 = (l < cnt)     ? (int)ev[s0 + l] : 0;
    int pc1 = (8 + l < cnt) ? (int)ev[s0 + 8 + l] : 0;
    for (int base = 0; base < cnt; base += 16) {
        int n0 = base + 16 + l;
        int n1 = base + 24 + l;
        int pn0 = (n0 < cnt) ? (int)ev[s0 + n0] : 0;   // prefetch next batch
        int pn1 = (n1 < cnt) ? (int)ev[s0 + n1] : 0;
        int pj[16];
        #pragma unroll
        for (int j = 0; j < 8; ++j) {
            pj[j]     = __shfl(pc0, gl | j);
            pj[8 + j] = __shfl(pc1, gl | j);
        }
        // 16 asm gathers, all in flight before one drain (compiler can't
        // collapse: the 16 "=v" outputs are simultaneously live).
        half8 xv[16];
        #pragma unroll
        for (int j = 0; j < 16; ++j) {
            unsigned off = (unsigned)(pj[j] & 0x3FFFF) * 128u + (unsigned)lb;
            asm volatile("global_load_dwordx4 %0, %1, %2"
                         : "=v"(xv[j]) : "v"(off), "s"(xh) : "memory");
        }
        asm volatile("s_waitcnt vmcnt(0)" ::: "memory");
        __builtin_amdgcn_sched_barrier(0);   // rule #18: fence reg-only uses
        #pragma unroll
        for (int j = 0; j < 16; ++j) {
            float vj = (float)((unsigned)pj[j] >> 18) * inv;
            #pragma unroll
            for (int k = 0; k < 8; ++k)
                acc[k] = fmaf(vj, (float)xv[j][k], acc[k]);
        }
        pc0 = pn0;
        pc1 = pn1;
    }
    int o = row * 64 + l * 8;
    if (MODE == 0) {
        half8 st;
        #pragma unroll
        for (int k = 0; k < 8; ++k) st[k] = (half_t)acc[k];
        *(half8*)(yh + o) = st;
    } else {
        const half8 a0 = *(const half8*)(x0h + o);   // X0 (fp16)
        const half8 a1 = *(const half8*)(y1h + o);   // Y1 (fp16)
        const half8 a2 = *(const half8*)(xh + o);    // Y2 (linear read)
        float r[8];
        #pragma unroll
        for (int k = 0; k < 8; ++k)
            r[k] = ((float)a0[k] + (float)a1[k] + (float)a2[k] + acc[k]) * 0.25f;
        *(float4*)(out + o)     = make_float4(r[0], r[1], r[2], r[3]);
        *(float4*)(out + o + 4) = make_float4(r[4], r[5], r[6], r[7]);
    }
}

extern "C" void kernel_launch(void* const* d_in, const int* in_sizes, int n_in,
                              void* d_out, int out_size, void* d_ws, size_t ws_size,
                              hipStream_t stream) {
    const float* ue   = (const float*)d_in[0];
    const float* ie   = (const float*)d_in[1];
    const int*   rows = (const int*)d_in[2];
    const int*   cols = (const int*)d_in[3];
    const float* vals = (const float*)d_in[4];
    float* out = (float*)d_out;

    // Workspace: X0h [XN fp16 = 19.2MB] | Y1h [19.2MB] | Y2h [19.2MB]
    //   (stg aliases Y1h..Y2h: NB*BPC*8B = 28.2MB < 38.4MB, dead before spmm
    //    layer 1 writes Y1h) | ev [E*4 = 9.6MB] | rp [NN+1] | pcnt [NB*16].
    //   Total ~68 MB.
    half_t*   X0h   = (half_t*)d_ws;
    half_t*   Y1h   = X0h + XN;
    half_t*   Y2h   = Y1h + XN;
    int2*     stg   = (int2*)Y1h;
    unsigned* ev    = (unsigned*)(Y2h + XN);
    int*      rp    = (int*)(ev + E);
    int*      pcnt  = rp + NN + 4;

    (void)hipMemsetAsync(pcnt, 0, NB * 16 * sizeof(int), stream);
    k_pre<<<BGRID + DGRID, BIN_T, 0, stream>>>(rows, cols, vals, stg, pcnt,
                                               ue, ie, X0h);
    k_bsort<<<NB, 1024, 0, stream>>>(stg, pcnt, rp, ev);

    int sgrid = (NN + 31) / 32;   // 32 rows per block (4 waves x 8 rows)
    k_spmm<0><<<sgrid, 256, 0, stream>>>(rp, ev, X0h, Y1h, nullptr, nullptr, nullptr); // Y1=A*X0
    k_spmm<0><<<sgrid, 256, 0, stream>>>(rp, ev, Y1h, Y2h, nullptr, nullptr, nullptr); // Y2=A*Y1
    k_spmm<1><<<sgrid, 256, 0, stream>>>(rp, ev, Y2h, nullptr, X0h, Y1h, out);         // combine
}